// Round 3
// 259.689 us; speedup vs baseline: 1.0591x; 1.0591x over previous
//
#include <hip/hip_runtime.h>

#define STEPS 30
#define HID 32
#define HALF_H 16
#define NG 8                     // 8 half2 groups = 16 hidden units per lane
#define TPB 256
#define EPB (TPB / 2)            // 128 elements per block (2 lanes per element)
#define LDS_STRIDE (STEPS + 1)   // 31: odd stride -> conflict-free per-element column reads

typedef _Float16 h2 __attribute__((ext_vector_type(2)));

// v_cvt_pkrtz_f16_f32: one instruction packs two f32 -> half2.
// Builtin returns __fp16 ext_vector(2); bit_cast to our _Float16 vector type.
static __device__ __forceinline__ h2 pkrtz(float x, float y) {
    return __builtin_bit_cast(h2, __builtin_amdgcn_cvt_pkrtz(x, y));
}
// v_pk_fma_f16 (full-rate VOP3P on 32-bit regs)
static __device__ __forceinline__ h2 h2fma(h2 a, h2 b, h2 c) {
    return __builtin_elementwise_fma(a, b, c);
}
// v_pk_max_f16
static __device__ __forceinline__ h2 h2max(h2 a, h2 b) {
    return __builtin_elementwise_max(a, b);
}

__global__ __launch_bounds__(TPB, 4) void hedge_kernel(
    const float* __restrict__ S,
    const float* __restrict__ W1,
    const float* __restrict__ b1,
    const float* __restrict__ W2,
    const float* __restrict__ b2,
    const float* __restrict__ a_init,
    float* __restrict__ out)
{
    __shared__ float tile[EPB * LDS_STRIDE];   // 128*31*4 = 15872 B
    const int tid  = threadIdx.x;
    const int half = tid & 1;                  // which 16 hidden units this lane owns
    const int el   = tid >> 1;                 // local element index [0,128)
    const long long base = (long long)blockIdx.x * (EPB * STEPS);

    // ---- Stage S tile (128 elems x 30 steps, 3840 floats) coalesced into padded LDS ----
    #pragma unroll
    for (int k = 0; k < (EPB * STEPS) / TPB; ++k) {   // 15 iters
        int idx = tid + k * TPB;
        float v = S[base + idx];
        int row = idx / STEPS;
        int col = idx - row * STEPS;
        tile[row * LDS_STRIDE + col] = v;
    }

    // ---- Per-lane weight slice, packed to half2 in VGPRs (one 32b reg per 2 units) ----
    const int j0 = half * HALF_H;
    h2 wa[NG], wc[NG], we[NG], wb[NG], w2[NG];
    #pragma unroll
    for (int q = 0; q < 4; ++q) {                     // 4 float4 = 16 floats per array
        float4 va = ((const float4*)(W1 + 0 * HID + j0))[q];  // coeff of s
        float4 vc = ((const float4*)(W1 + 1 * HID + j0))[q];  // coeff of d_prev
        float4 ve = ((const float4*)(W1 + 2 * HID + j0))[q];  // coeff of h
        float4 vb = ((const float4*)(b1 + j0))[q];
        float4 v2 = ((const float4*)(W2 + j0))[q];
        wa[2*q] = pkrtz(va.x, va.y); wa[2*q+1] = pkrtz(va.z, va.w);
        wc[2*q] = pkrtz(vc.x, vc.y); wc[2*q+1] = pkrtz(vc.z, vc.w);
        we[2*q] = pkrtz(ve.x, ve.y); we[2*q+1] = pkrtz(ve.z, ve.w);
        wb[2*q] = pkrtz(vb.x, vb.y); wb[2*q+1] = pkrtz(vb.z, vb.w);
        w2[2*q] = pkrtz(v2.x, v2.y); w2[2*q+1] = pkrtz(v2.z, v2.w);
    }
    const float bias2 = b2[0];
    float d = a_init[0];                       // fp32 carries
    float h = 0.0f;
    const h2 zero2 = {(_Float16)0.0f, (_Float16)0.0f};
    __syncthreads();

    // ---- Recurrence: lane pair (2k, 2k+1) = one element; 16 hidden units per lane.
    //      Packed f16 pre-activation + ReLU, fp32-accumulating dot2 for the W2 reduce:
    //      5 VALU per 2 units vs 10 scalar fp32. ----
    float* my = &tile[el * LDS_STRIDE];
    #pragma unroll
    for (int t = 0; t < STEPS; ++t) {
        const float s = my[t];                 // both lanes read same addr: LDS broadcast
        const h2 s2 = pkrtz(s, s);             // 1 instr broadcasts into packed half2
        const h2 d2 = pkrtz(d, d);
        const h2 h2v = pkrtz(h, h);
        float a0 = 0.f, a1 = 0.f, a2 = 0.f, a3 = 0.f;
        #pragma unroll
        for (int g = 0; g < NG; g += 4) {
            h2 t0 = h2fma(wa[g+0], s2, h2fma(wc[g+0], d2, h2fma(we[g+0], h2v, wb[g+0])));
            h2 t1 = h2fma(wa[g+1], s2, h2fma(wc[g+1], d2, h2fma(we[g+1], h2v, wb[g+1])));
            h2 t2 = h2fma(wa[g+2], s2, h2fma(wc[g+2], d2, h2fma(we[g+2], h2v, wb[g+2])));
            h2 t3 = h2fma(wa[g+3], s2, h2fma(wc[g+3], d2, h2fma(we[g+3], h2v, wb[g+3])));
            // v_dot2_f32_f16: exact f16 products, fp32 accumulate
            a0 = __builtin_amdgcn_fdot2(h2max(t0, zero2), w2[g+0], a0, false);
            a1 = __builtin_amdgcn_fdot2(h2max(t1, zero2), w2[g+1], a1, false);
            a2 = __builtin_amdgcn_fdot2(h2max(t2, zero2), w2[g+2], a2, false);
            a3 = __builtin_amdgcn_fdot2(h2max(t3, zero2), w2[g+3], a3, false);
        }
        float acc = (a0 + a1) + (a2 + a3);
        acc += __shfl_xor(acc, 1, 64);         // combine the two 16-unit halves
        const float dn = bias2 + acc;          // both lanes hold full d_t (fp32)
        h = fmaf(0.2f, dn, 0.8f * h);
        d = dn;
        if (!half) my[t] = dn;                 // S[t] consumed; slot reused for output
    }
    __syncthreads();

    // ---- Dump outputs coalesced (same flat layout as S) ----
    #pragma unroll
    for (int k = 0; k < (EPB * STEPS) / TPB; ++k) {   // 15 iters
        int idx = tid + k * TPB;
        int row = idx / STEPS;
        int col = idx - row * STEPS;
        out[base + idx] = tile[row * LDS_STRIDE + col];
    }
}

extern "C" void kernel_launch(void* const* d_in, const int* in_sizes, int n_in,
                              void* d_out, int out_size, void* d_ws, size_t ws_size,
                              hipStream_t stream) {
    const float* S      = (const float*)d_in[0];
    const float* W1     = (const float*)d_in[1];
    const float* b1     = (const float*)d_in[2];
    const float* W2     = (const float*)d_in[3];
    const float* b2     = (const float*)d_in[4];
    const float* a_init = (const float*)d_in[5];
    float* out = (float*)d_out;

    const int batch = in_sizes[0] / STEPS;    // 1048576
    const int grid  = batch / EPB;            // 8192 blocks of 128 elements
    hedge_kernel<<<grid, TPB, 0, stream>>>(S, W1, b1, W2, b2, a_init, out);
}